// Round 5
// baseline (520.828 us; speedup 1.0000x reference)
//
#include <hip/hip_runtime.h>
#include <stdint.h>
#include <math.h>

#define DIM 4096
#define NH 32
#define NKV 8
#define HD 128
#define SEQ 2048
#define KVDIM (NKV * HD)   // 1024
#define QKVDIM (DIM + 2 * KVDIM)   // 6144

typedef __bf16 bf16x8 __attribute__((ext_vector_type(8)));
typedef float floatx4 __attribute__((ext_vector_type(4)));
typedef uint16_t u16x8 __attribute__((ext_vector_type(8)));

#define AS1C(p) ((const __attribute__((address_space(1))) void*)(p))
#define AS3(p)  ((__attribute__((address_space(3))) void*)(p))

__device__ __forceinline__ float b2f(uint16_t u) {
    union { uint32_t i; float f; } v; v.i = ((uint32_t)u) << 16; return v.f;
}
__device__ __forceinline__ uint16_t f2b(float f) {
    union { float f; uint32_t i; } v; v.f = f;
    uint32_t r = v.i + 0x7fffu + ((v.i >> 16) & 1u);   // RTNE
    return (uint16_t)(r >> 16);
}

// Load 8 logical bf16 elements starting at element index e of buffer p,
// where p is bf16 (isf32=false) or f32 (isf32=true; convert to bf16).
__device__ __forceinline__ u16x8 ldchunk(const void* p, bool isf32, size_t e) {
    if (isf32) {
        const float* fp = (const float*)p + e;
        u16x8 r;
#pragma unroll
        for (int j = 0; j < 8; ++j) r[j] = f2b(fp[j]);
        return r;
    }
    return *(const u16x8*)((const uint16_t*)p + e);
}

// ---------------------------------------------------------------------------
// dtype detector: flag 0 = bf16 inputs, 1 = f32 inputs.
// ---------------------------------------------------------------------------
__global__ void detect_k(const uint16_t* __restrict__ x, int* __restrict__ flag) {
    __shared__ int cnt;
    if (threadIdx.x == 0) cnt = 0;
    __syncthreads();
    int bad = 0;
    for (int i = threadIdx.x; i < 4096; i += 256) {
        float v = b2f(x[i]);
        if (!(fabsf(v) < 1e6f)) bad++;   // NaN compares false -> counted
    }
    atomicAdd(&cnt, bad);
    __syncthreads();
    if (threadIdx.x == 0) *flag = (cnt > 256) ? 1 : 0;
}

// ---------------------------------------------------------------------------
// convert kernel: f32 -> bf16 (flag==1) or bf16 copy (flag==0). n % 8 == 0.
// ---------------------------------------------------------------------------
__global__ __launch_bounds__(256) void conv_k(const void* __restrict__ src,
                                              uint16_t* __restrict__ dst,
                                              size_t n,
                                              const int* __restrict__ flagp) {
    const int f = *flagp;
    size_t i = ((size_t)blockIdx.x * blockDim.x + threadIdx.x) * 8;
    const size_t stride = (size_t)gridDim.x * blockDim.x * 8;
    if (f) {
        for (; i < n; i += stride) {
            const float* s = (const float*)src + i;
            u16x8 r;
#pragma unroll
            for (int j = 0; j < 8; ++j) r[j] = f2b(s[j]);
            *(u16x8*)(dst + i) = r;
        }
    } else {
        for (; i < n; i += stride)
            *(u16x8*)(dst + i) = *(const u16x8*)((const uint16_t*)src + i);
    }
}

// ---------------------------------------------------------------------------
// fused 4-region convert: one launch for x, wq, wk, wv (saves launch gaps).
// ---------------------------------------------------------------------------
__global__ __launch_bounds__(256) void conv4_k(const void* __restrict__ s0,
                                               const void* __restrict__ s1,
                                               const void* __restrict__ s2,
                                               const void* __restrict__ s3,
                                               uint16_t* __restrict__ d0,
                                               uint16_t* __restrict__ d1,
                                               uint16_t* __restrict__ d2,
                                               uint16_t* __restrict__ d3,
                                               size_t n0, size_t n1,
                                               size_t n2, size_t n3,
                                               const int* __restrict__ flagp) {
    const int f = *flagp;
    const size_t tot = (n0 + n1 + n2 + n3) >> 3;
    size_t c = (size_t)blockIdx.x * blockDim.x + threadIdx.x;
    const size_t stride = (size_t)gridDim.x * blockDim.x;
    for (; c < tot; c += stride) {
        size_t off = c << 3;
        const void* sp; uint16_t* dp;
        if (off < n0) { sp = s0; dp = d0; }
        else {
            off -= n0;
            if (off < n1) { sp = s1; dp = d1; }
            else {
                off -= n1;
                if (off < n2) { sp = s2; dp = d2; }
                else { off -= n2; sp = s3; dp = d3; }
            }
        }
        if (f) {
            const float* s = (const float*)sp + off;
            u16x8 r;
#pragma unroll
            for (int j = 0; j < 8; ++j) r[j] = f2b(s[j]);
            *(u16x8*)(dp + off) = r;
        } else {
            *(u16x8*)(dp + off) = *(const u16x8*)((const uint16_t*)sp + off);
        }
    }
}

// ---------------------------------------------------------------------------
// Legacy NT GEMM (fallback when workspace too small): dynamic dtype operands.
// out_trans: write C^T (bf16) at CT[col][row], ldc = row stride of CT.
// ---------------------------------------------------------------------------
__global__ __launch_bounds__(256) void gemm_nt(const void* __restrict__ A,
                                               const void* __restrict__ B,
                                               void* __restrict__ C,
                                               int K, int ldc,
                                               const int* __restrict__ flagp,
                                               int a_dyn, int b_dyn, int out_dyn,
                                               int out_trans) {
    __shared__ uint16_t As[128 * 64];
    __shared__ uint16_t Bs[128 * 64];
    const int f = *flagp;
    const bool af32 = a_dyn && f, bf32 = b_dyn && f, of32 = out_dyn && f;
    const int tid = threadIdx.x;
    const int wave = tid >> 6, lane = tid & 63;
    const int wh = wave >> 1, ww = wave & 1;
    const int quad = lane >> 4, l16 = lane & 15;
    const int m0 = blockIdx.x * 128;
    const int n0 = blockIdx.y * 128;

    floatx4 acc[4][4] = {};

    for (int k0 = 0; k0 < K; k0 += 64) {
        __syncthreads();
#pragma unroll
        for (int it = 0; it < 4; ++it) {
            int id = tid + it * 256;
            int row = id >> 3, slot = id & 7;
            int c8 = ((slot ^ (row & 7)) << 3);
            u16x8 va = ldchunk(A, af32, (size_t)(m0 + row) * K + k0 + c8);
            *(u16x8*)(As + row * 64 + slot * 8) = va;
            u16x8 vb = ldchunk(B, bf32, (size_t)(n0 + row) * K + k0 + c8);
            *(u16x8*)(Bs + row * 64 + slot * 8) = vb;
        }
        __syncthreads();
#pragma unroll
        for (int ks = 0; ks < 2; ++ks) {
            bf16x8 af[4], bf[4];
#pragma unroll
            for (int mi = 0; mi < 4; ++mi) {
                int r = wh * 64 + mi * 16 + l16;
                int slot = (ks * 4 + quad) ^ (r & 7);
                af[mi] = *(const bf16x8*)(As + r * 64 + slot * 8);
            }
#pragma unroll
            for (int ni = 0; ni < 4; ++ni) {
                int r = ww * 64 + ni * 16 + l16;
                int slot = (ks * 4 + quad) ^ (r & 7);
                bf[ni] = *(const bf16x8*)(Bs + r * 64 + slot * 8);
            }
#pragma unroll
            for (int mi = 0; mi < 4; ++mi)
#pragma unroll
                for (int ni = 0; ni < 4; ++ni)
                    acc[mi][ni] = __builtin_amdgcn_mfma_f32_16x16x32_bf16(
                        af[mi], bf[ni], acc[mi][ni], 0, 0, 0);
        }
    }
#pragma unroll
    for (int mi = 0; mi < 4; ++mi) {
#pragma unroll
        for (int ni = 0; ni < 4; ++ni) {
            int row = m0 + wh * 64 + mi * 16 + quad * 4;
            int col = n0 + ww * 64 + ni * 16 + l16;
            if (out_trans) {
                uint64_t pack = 0;
#pragma unroll
                for (int i = 0; i < 4; ++i)
                    pack |= (uint64_t)f2b(acc[mi][ni][i]) << (16 * i);
                *(uint64_t*)((uint16_t*)C + (size_t)col * ldc + row) = pack;
            } else if (of32) {
#pragma unroll
                for (int i = 0; i < 4; ++i)
                    ((float*)C)[(size_t)(row + i) * ldc + col] = acc[mi][ni][i];
            } else {
#pragma unroll
                for (int i = 0; i < 4; ++i)
                    ((uint16_t*)C)[(size_t)(row + i) * ldc + col] = f2b(acc[mi][ni][i]);
            }
        }
    }
}

// ---------------------------------------------------------------------------
// Fast NT GEMM: pure bf16 operands, global_load_lds(16B) staging.
// XCD-chunked bijective blockIdx swizzle when nwg%8==0.
// out_mode: 0 = bf16 row-major; 1 = f32-if-flag row-major.
// ---------------------------------------------------------------------------
__global__ __launch_bounds__(256) void gemm_bf(const uint16_t* __restrict__ A,
                                               const uint16_t* __restrict__ B,
                                               void* __restrict__ C,
                                               int K, int ldc,
                                               const int* __restrict__ flagp,
                                               int out_mode) {
    __shared__ uint16_t As[128 * 64];
    __shared__ uint16_t Bs[128 * 64];
    const bool of32 = (out_mode == 1) && (*flagp);
    const int tid = threadIdx.x;
    const int wave = tid >> 6, lane = tid & 63;
    const int wh = wave >> 1, ww = wave & 1;
    const int quad = lane >> 4, l16 = lane & 15;

    int nwg = gridDim.x * gridDim.y;
    int id = blockIdx.y * gridDim.x + blockIdx.x;
    if ((nwg & 7) == 0) {
        int cpx = nwg >> 3;
        id = (id & 7) * cpx + (id >> 3);
    }
    const int m0 = (id % gridDim.x) * 128;
    const int n0 = (id / gridDim.x) * 128;

    floatx4 acc[4][4] = {};

    for (int k0 = 0; k0 < K; k0 += 64) {
        __syncthreads();   // prior iteration's LDS reads done
#pragma unroll
        for (int it = 0; it < 4; ++it) {
            int idc = tid + it * 256;          // chunk id 0..1023
            int row = idc >> 3, slot = idc & 7;
            int c8 = ((slot ^ (row & 7)) << 3);
            __builtin_amdgcn_global_load_lds(
                AS1C(A + (size_t)(m0 + row) * K + k0 + c8),
                AS3(As + (size_t)(it * 256 + wave * 64) * 8), 16, 0, 0);
            __builtin_amdgcn_global_load_lds(
                AS1C(B + (size_t)(n0 + row) * K + k0 + c8),
                AS3(Bs + (size_t)(it * 256 + wave * 64) * 8), 16, 0, 0);
        }
        __syncthreads();   // vmcnt(0) drain + barrier: tiles visible
#pragma unroll
        for (int ks = 0; ks < 2; ++ks) {
            bf16x8 af[4], bf[4];
#pragma unroll
            for (int mi = 0; mi < 4; ++mi) {
                int r = wh * 64 + mi * 16 + l16;
                int slot = (ks * 4 + quad) ^ (r & 7);
                af[mi] = *(const bf16x8*)(As + r * 64 + slot * 8);
            }
#pragma unroll
            for (int ni = 0; ni < 4; ++ni) {
                int r = ww * 64 + ni * 16 + l16;
                int slot = (ks * 4 + quad) ^ (r & 7);
                bf[ni] = *(const bf16x8*)(Bs + r * 64 + slot * 8);
            }
#pragma unroll
            for (int mi = 0; mi < 4; ++mi)
#pragma unroll
                for (int ni = 0; ni < 4; ++ni)
                    acc[mi][ni] = __builtin_amdgcn_mfma_f32_16x16x32_bf16(
                        af[mi], bf[ni], acc[mi][ni], 0, 0, 0);
        }
    }
    // epilogue: C/D layout row = quad*4 + i, col = lane&15
#pragma unroll
    for (int mi = 0; mi < 4; ++mi) {
#pragma unroll
        for (int ni = 0; ni < 4; ++ni) {
            int row = m0 + wh * 64 + mi * 16 + quad * 4;
            int col = n0 + ww * 64 + ni * 16 + l16;
            if (of32) {
#pragma unroll
                for (int i = 0; i < 4; ++i)
                    ((float*)C)[(size_t)(row + i) * ldc + col] = acc[mi][ni][i];
            } else {
#pragma unroll
                for (int i = 0; i < 4; ++i)
                    ((uint16_t*)C)[(size_t)(row + i) * ldc + col] = f2b(acc[mi][ni][i]);
            }
        }
    }
}

// ---------------------------------------------------------------------------
// Fused QKV projection GEMM: A = xb [SEQ][DIM], W = [QKVDIM][DIM] (rows
// 0..4095 wq, 4096..5119 wk, 5120..6143 wv). Epilogue routes by n0:
// Q -> Qo row-major [SEQ][DIM]; K -> Ko row-major [SEQ][KVDIM];
// V -> VoT transposed [KVDIM][SEQ] (attn consumes V^T).
// grid 16x48 = 768 blocks (3/CU), XCD-chunked swizzle.
// ---------------------------------------------------------------------------
__global__ __launch_bounds__(256) void gemm_qkv(const uint16_t* __restrict__ A,
                                                const uint16_t* __restrict__ W,
                                                uint16_t* __restrict__ Qo,
                                                uint16_t* __restrict__ Ko,
                                                uint16_t* __restrict__ VoT) {
    __shared__ uint16_t As[128 * 64];
    __shared__ uint16_t Bs[128 * 64];
    const int tid = threadIdx.x;
    const int wave = tid >> 6, lane = tid & 63;
    const int wh = wave >> 1, ww = wave & 1;
    const int quad = lane >> 4, l16 = lane & 15;

    int nwg = gridDim.x * gridDim.y;           // 768
    int id = blockIdx.y * gridDim.x + blockIdx.x;
    int cpx = nwg >> 3;
    id = (id & 7) * cpx + (id >> 3);           // XCD-chunked, M fastest
    const int m0 = (id % gridDim.x) * 128;
    const int n0 = (id / gridDim.x) * 128;
    const int K = DIM;

    floatx4 acc[4][4] = {};

    for (int k0 = 0; k0 < K; k0 += 64) {
        __syncthreads();
#pragma unroll
        for (int it = 0; it < 4; ++it) {
            int idc = tid + it * 256;
            int row = idc >> 3, slot = idc & 7;
            int c8 = ((slot ^ (row & 7)) << 3);
            __builtin_amdgcn_global_load_lds(
                AS1C(A + (size_t)(m0 + row) * K + k0 + c8),
                AS3(As + (size_t)(it * 256 + wave * 64) * 8), 16, 0, 0);
            __builtin_amdgcn_global_load_lds(
                AS1C(W + (size_t)(n0 + row) * K + k0 + c8),
                AS3(Bs + (size_t)(it * 256 + wave * 64) * 8), 16, 0, 0);
        }
        __syncthreads();
#pragma unroll
        for (int ks = 0; ks < 2; ++ks) {
            bf16x8 af[4], bf[4];
#pragma unroll
            for (int mi = 0; mi < 4; ++mi) {
                int r = wh * 64 + mi * 16 + l16;
                int slot = (ks * 4 + quad) ^ (r & 7);
                af[mi] = *(const bf16x8*)(As + r * 64 + slot * 8);
            }
#pragma unroll
            for (int ni = 0; ni < 4; ++ni) {
                int r = ww * 64 + ni * 16 + l16;
                int slot = (ks * 4 + quad) ^ (r & 7);
                bf[ni] = *(const bf16x8*)(Bs + r * 64 + slot * 8);
            }
#pragma unroll
            for (int mi = 0; mi < 4; ++mi)
#pragma unroll
                for (int ni = 0; ni < 4; ++ni)
                    acc[mi][ni] = __builtin_amdgcn_mfma_f32_16x16x32_bf16(
                        af[mi], bf[ni], acc[mi][ni], 0, 0, 0);
        }
    }
    // epilogue: slice-routed (n0 uniform per block; slices 128-aligned)
#pragma unroll
    for (int mi = 0; mi < 4; ++mi) {
#pragma unroll
        for (int ni = 0; ni < 4; ++ni) {
            int row = m0 + wh * 64 + mi * 16 + quad * 4;
            int col = n0 + ww * 64 + ni * 16 + l16;
            if (n0 < DIM) {
#pragma unroll
                for (int i = 0; i < 4; ++i)
                    Qo[(size_t)(row + i) * DIM + col] = f2b(acc[mi][ni][i]);
            } else if (n0 < DIM + KVDIM) {
                int c = col - DIM;
#pragma unroll
                for (int i = 0; i < 4; ++i)
                    Ko[(size_t)(row + i) * KVDIM + c] = f2b(acc[mi][ni][i]);
            } else {
                int c = col - DIM - KVDIM;
                uint64_t pack = 0;
#pragma unroll
                for (int i = 0; i < 4; ++i)
                    pack |= (uint64_t)f2b(acc[mi][ni][i]) << (16 * i);
                *(uint64_t*)(VoT + (size_t)c * SEQ + row) = pack;
            }
        }
    }
}

// ---------------------------------------------------------------------------
// Fused RoPE: one launch for Q [SEQ][DIM] and K [SEQ][KVDIM]. Head-slot
// hh in [0,40): hh<32 -> Q head hh, else K head hh-32. hh is wave-uniform.
// ---------------------------------------------------------------------------
__global__ void rope2_k(uint16_t* __restrict__ Qb, uint16_t* __restrict__ Kb) {
    int id = blockIdx.x * blockDim.x + threadIdx.x;
    int i = id & 63;
    int rest = id >> 6;
    int hh = rest % (NH + NKV);
    int t = rest / (NH + NKV);
    uint16_t* p = (hh < NH)
        ? (Qb + (size_t)t * DIM + hh * HD + 2 * i)
        : (Kb + (size_t)t * KVDIM + (hh - NH) * HD + 2 * i);
    float e = b2f(p[0]), o = b2f(p[1]);
    float freq = exp2f(-(float)(2 * i) * (18.93156857f / 128.0f));
    float ang = (float)t * freq;
    float s, c;
    sincosf(ang, &s, &c);
    p[0] = f2b(e * c - o * s);
    p[1] = f2b(e * s + o * c);
}

// ---------------------------------------------------------------------------
// Flash attention (causal, GQA rep=4). 512 threads = 8 waves; wave w owns
// q-rows [w*16, w*16+16), ALL keys -> softmax fully wave-local, P buffer
// rows are wave-exclusive (no cross-wave barrier between QK^T and PV).
// Grid = 512 blocks (one q-tile each) at 2 blocks/CU (LDS exactly 80 KB,
// Q fragments loaded global->reg, no Qs buffer) -> 4 waves/SIMD.
// Block order: group g (=bid>>5) -> qt = g<8 ? 15-g : g-8, so co-resident
// pairs (b, b+256) sum to a uniform 34 tile-units; heavy blocks first.
// K/V double-buffered; next tile prefetched via global_load_lds, drained at
// the single end-of-tile __syncthreads. V arrives pre-transposed (VgT).
// ---------------------------------------------------------------------------
__global__ __launch_bounds__(512, 4) void attn_k(const uint16_t* __restrict__ Q,
                                                 const uint16_t* __restrict__ Kg,
                                                 const uint16_t* __restrict__ VgT,
                                                 uint16_t* __restrict__ O) {
    __shared__ uint16_t Ks[2][64 * 128];   // 32 KB
    __shared__ uint16_t Vt[2][128 * 64];   // 32 KB
    __shared__ uint16_t Pb[128 * 64];      // 16 KB   -> 80 KB total

    const int tid = threadIdx.x;
    const int wave = tid >> 6, lane = tid & 63;
    const int quad = lane >> 4, l16 = lane & 15;

    const int head = blockIdx.x & 31;
    const int g16 = blockIdx.x >> 5;                    // 0..15
    const int qt = (g16 < 8) ? (15 - g16) : (g16 - 8);  // pair-balanced order
    const int kvh = head >> 2;
    const int q0 = qt * 128;
    const uint16_t* Vh = VgT + (size_t)kvh * HD * SEQ;

    const float scale = 0.08838834764831845f;  // 1/sqrt(128)
    const float LOG2E = 1.44269504f;

    auto stage_kv = [&](int buf, int k0s) {
#pragma unroll
        for (int it = 0; it < 2; ++it) {
            int id = tid + it * 512;
            int row = id >> 4, slot = id & 15;
            int c8 = ((slot ^ (row & 7)) << 3);
            __builtin_amdgcn_global_load_lds(
                AS1C(Kg + (size_t)(k0s + row) * KVDIM + kvh * HD + c8),
                AS3(Ks[buf] + (size_t)(it * 512 + wave * 64) * 8), 16, 0, 0);
        }
#pragma unroll
        for (int it = 0; it < 2; ++it) {
            int id = tid + it * 512;
            int d = id >> 3, slot = id & 7;
            int c8 = ((slot ^ (d & 7)) << 3);
            __builtin_amdgcn_global_load_lds(
                AS1C(Vh + (size_t)d * SEQ + k0s + c8),
                AS3(Vt[buf] + (size_t)(it * 512 + wave * 64) * 8), 16, 0, 0);
        }
    };

    // Q fragments: direct global -> registers (once per block, no LDS)
    bf16x8 qf[4];
    {
        const uint16_t* qrow = Q + (size_t)(q0 + wave * 16 + l16) * DIM + head * HD;
#pragma unroll
        for (int ks = 0; ks < 4; ++ks)
            qf[ks] = *(const bf16x8*)(qrow + (ks * 4 + quad) * 8);
    }

    floatx4 acc_o[8] = {};
    float m_run[4], l_run[4];
#pragma unroll
    for (int i = 0; i < 4; ++i) { m_run[i] = -__builtin_inff(); l_run[i] = 0.f; }

    const int nkt = 2 * qt + 2;
    stage_kv(0, 0);
    __syncthreads();   // tile 0 visible

    for (int t = 0; t < nkt; ++t) {
        const int k0 = t * 64;
        const bool diag = (t >= 2 * qt);
        const int cur = t & 1;

        // prefetch next tile into the other buffer
        if (t + 1 < nkt) stage_kv((t + 1) & 1, (t + 1) * 64);
        __builtin_amdgcn_sched_barrier(0);   // pin prefetch issue early

        // S = Q K^T
        floatx4 acc_s[4] = {};
        __builtin_amdgcn_s_setprio(1);
#pragma unroll
        for (int ks = 0; ks < 4; ++ks) {
            bf16x8 kf[4];
#pragma unroll
            for (int ni = 0; ni < 4; ++ni) {
                int r = ni * 16 + l16;
                int slot = (ks * 4 + quad) ^ (r & 7);
                kf[ni] = *(const bf16x8*)(Ks[cur] + r * 128 + slot * 8);
            }
#pragma unroll
            for (int ni = 0; ni < 4; ++ni)
                acc_s[ni] = __builtin_amdgcn_mfma_f32_16x16x32_bf16(
                    qf[ks], kf[ni], acc_s[ni], 0, 0, 0);
        }
        __builtin_amdgcn_s_setprio(0);

        // scale + causal mask
#pragma unroll
        for (int ni = 0; ni < 4; ++ni)
#pragma unroll
            for (int i = 0; i < 4; ++i) {
                float s = acc_s[ni][i] * scale;
                if (diag) {
                    int ql = q0 + wave * 16 + quad * 4 + i;
                    int kl = k0 + ni * 16 + l16;
                    if (kl > ql) s = -__builtin_inff();
                }
                acc_s[ni][i] = s;
            }

        // wave-local online softmax; write P (bf16) into wave-owned rows
        float alpha[4];
#pragma unroll
        for (int i = 0; i < 4; ++i) {
            float v = fmaxf(fmaxf(acc_s[0][i], acc_s[1][i]),
                            fmaxf(acc_s[2][i], acc_s[3][i]));
#pragma unroll
            for (int off = 1; off < 16; off <<= 1)
                v = fmaxf(v, __shfl_xor(v, off));
            float mn = fmaxf(m_run[i], v);
            alpha[i] = exp2f((m_run[i] - mn) * LOG2E);
            m_run[i] = mn;

            int ql = wave * 16 + quad * 4 + i;
            float sum = 0.f;
#pragma unroll
            for (int ni = 0; ni < 4; ++ni) {
                float p = exp2f((acc_s[ni][i] - mn) * LOG2E);
                sum += p;
                int key = ni * 16 + l16;
                int slot = ((key >> 3) ^ (ql & 7) ^ ((ql >> 3) & 7)) & 7;
                Pb[ql * 64 + slot * 8 + (key & 7)] = f2b(p);
            }
#pragma unroll
            for (int off = 1; off < 16; off <<= 1)
                sum += __shfl_xor(sum, off);
            l_run[i] = l_run[i] * alpha[i] + sum;
        }

        // rescale O accumulator
#pragma unroll
        for (int ni = 0; ni < 8; ++ni)
#pragma unroll
            for (int i = 0; i < 4; ++i)
                acc_o[ni][i] *= alpha[i];

        // O += P V  (P rows wave-exclusive: same-wave DS order suffices)
        __builtin_amdgcn_s_setprio(1);
#pragma unroll
        for (int ks2 = 0; ks2 < 2; ++ks2) {
            bf16x8 pf, vf[8];
            {
                int r = wave * 16 + l16;
                int slot = ((ks2 * 4 + quad) ^ (r & 7) ^ ((r >> 3) & 7)) & 7;
                pf = *(const bf16x8*)(Pb + r * 64 + slot * 8);
            }
#pragma unroll
            for (int ni = 0; ni < 8; ++ni) {
                int d = ni * 16 + l16;
                int slot = ((ks2 * 4 + quad) ^ (d & 7)) & 7;
                vf[ni] = *(const bf16x8*)(Vt[cur] + d * 64 + slot * 8);
            }
#pragma unroll
            for (int ni = 0; ni < 8; ++ni)
                acc_o[ni] = __builtin_amdgcn_mfma_f32_16x16x32_bf16(
                    pf, vf[ni], acc_o[ni], 0, 0, 0);
        }
        __builtin_amdgcn_s_setprio(0);

        __syncthreads();   // drains prefetch (vmcnt) + all LDS; next tile ready
    }

    // epilogue
#pragma unroll
    for (int i = 0; i < 4; ++i) {
        float inv = 1.0f / l_run[i];
        int row = q0 + wave * 16 + quad * 4 + i;
#pragma unroll
        for (int ni = 0; ni < 8; ++ni) {
            int col = head * HD + ni * 16 + l16;
            O[(size_t)row * DIM + col] = f2b(acc_o[ni][i] * inv);
        }
    }
}

extern "C" void kernel_launch(void* const* d_in, const int* in_sizes, int n_in,
                              void* d_out, int out_size, void* d_ws, size_t ws_size,
                              hipStream_t stream) {
    const void* x  = d_in[0];
    const void* wq = d_in[1];
    const void* wk = d_in[2];
    const void* wv = d_in[3];
    const void* wo = d_in[4];

    // fast-path ws layout (aliased, stream-ordered):
    //   [flag 256B][Kb 4M][VbT 4M][xb 16M][BIG 50.3M]
    //   BIG = Wqkv[6144][4096] during QKV gemm;
    //   then Ab = BIG[0:16.8M] (attn out), Wo = BIG+16.8M (wo bf16, 33.6M).
    int* flag = (int*)d_ws;
    uint16_t* Kb  = (uint16_t*)((char*)d_ws + 256);
    uint16_t* VbT = Kb + (size_t)SEQ * KVDIM;       // V^T: [KVDIM][SEQ]
    uint16_t* xb  = VbT + (size_t)SEQ * KVDIM;
    uint16_t* BIG = xb + (size_t)SEQ * DIM;
    uint16_t* Wqkv = BIG;
    uint16_t* Ab   = BIG;
    uint16_t* Wo   = BIG + (size_t)SEQ * DIM;
    // Q lives in d_out (dead before the final GEMM overwrites d_out)
    uint16_t* Qb = (uint16_t*)d_out;

    const size_t need = 256 + ((size_t)2 * SEQ * KVDIM     // Kb + VbT
                             + (size_t)SEQ * DIM           // xb
                             + (size_t)QKVDIM * DIM) * 2;  // BIG

    dim3 blk(256);
    detect_k<<<1, blk, 0, stream>>>((const uint16_t*)x, flag);

    if (ws_size >= need) {
        // fast path: fused pre-convert, fused QKV gemm, global_load_lds
        conv4_k<<<4096, blk, 0, stream>>>(
            x, wq, wk, wv,
            xb, Wqkv, Wqkv + (size_t)DIM * DIM, Wqkv + (size_t)(DIM + KVDIM) * DIM,
            (size_t)SEQ * DIM, (size_t)DIM * DIM,
            (size_t)KVDIM * DIM, (size_t)KVDIM * DIM, flag);
        gemm_qkv<<<dim3(SEQ / 128, QKVDIM / 128), blk, 0, stream>>>(
            xb, Wqkv, Qb, Kb, VbT);
        // Wqkv dead; Wo region (BIG+16.8M) safe to fill now
        conv_k<<<2048, blk, 0, stream>>>(wo, Wo, (size_t)DIM * DIM, flag);
        rope2_k<<<(SEQ * (NH + NKV) * 64) / 256, 256, 0, stream>>>(Qb, Kb);
        attn_k<<<NH * 16, dim3(512), 0, stream>>>(Qb, Kb, VbT, Ab);   // Ab = BIG[0:16.8M]
        gemm_bf<<<dim3(SEQ / 128, DIM / 128), blk, 0, stream>>>(Ab, Wo, d_out, DIM, DIM, flag, 1);
    } else {
        // legacy path: dynamic-dtype GEMMs, no extra workspace
        uint16_t* AbL = xb;   // legacy Ab right after VbT (within 'fixed' size)
        gemm_nt<<<dim3(SEQ / 128, DIM / 128), blk, 0, stream>>>(x, wq, Qb, DIM, DIM, flag, 1, 1, 0, 0);
        gemm_nt<<<dim3(SEQ / 128, KVDIM / 128), blk, 0, stream>>>(x, wk, Kb, DIM, KVDIM, flag, 1, 1, 0, 0);
        gemm_nt<<<dim3(SEQ / 128, KVDIM / 128), blk, 0, stream>>>(x, wv, VbT, DIM, SEQ, flag, 1, 1, 0, 1);
        rope2_k<<<(SEQ * (NH + NKV) * 64) / 256, 256, 0, stream>>>(Qb, Kb);
        attn_k<<<NH * 16, dim3(512), 0, stream>>>(Qb, Kb, VbT, AbL);
        gemm_nt<<<dim3(SEQ / 128, DIM / 128), blk, 0, stream>>>(AbL, wo, d_out, DIM, DIM, flag, 0, 1, 1, 0);
    }
}

// Round 6
// 494.359 us; speedup vs baseline: 1.0535x; 1.0535x over previous
//
#include <hip/hip_runtime.h>
#include <stdint.h>
#include <math.h>

#define DIM 4096
#define NH 32
#define NKV 8
#define HD 128
#define SEQ 2048
#define KVDIM (NKV * HD)   // 1024
#define QKVDIM (DIM + 2 * KVDIM)   // 6144

typedef __bf16 bf16x8 __attribute__((ext_vector_type(8)));
typedef float floatx4 __attribute__((ext_vector_type(4)));
typedef uint16_t u16x8 __attribute__((ext_vector_type(8)));

#define AS1C(p) ((const __attribute__((address_space(1))) void*)(p))
#define AS3(p)  ((__attribute__((address_space(3))) void*)(p))

__device__ __forceinline__ float b2f(uint16_t u) {
    union { uint32_t i; float f; } v; v.i = ((uint32_t)u) << 16; return v.f;
}
__device__ __forceinline__ uint16_t f2b(float f) {
    union { float f; uint32_t i; } v; v.f = f;
    uint32_t r = v.i + 0x7fffu + ((v.i >> 16) & 1u);   // RTNE
    return (uint16_t)(r >> 16);
}

// Load 8 logical bf16 elements starting at element index e of buffer p,
// where p is bf16 (isf32=false) or f32 (isf32=true; convert to bf16).
__device__ __forceinline__ u16x8 ldchunk(const void* p, bool isf32, size_t e) {
    if (isf32) {
        const float* fp = (const float*)p + e;
        u16x8 r;
#pragma unroll
        for (int j = 0; j < 8; ++j) r[j] = f2b(fp[j]);
        return r;
    }
    return *(const u16x8*)((const uint16_t*)p + e);
}

// ---------------------------------------------------------------------------
// dtype detector: flag 0 = bf16 inputs, 1 = f32 inputs.
// ---------------------------------------------------------------------------
__global__ void detect_k(const uint16_t* __restrict__ x, int* __restrict__ flag) {
    __shared__ int cnt;
    if (threadIdx.x == 0) cnt = 0;
    __syncthreads();
    int bad = 0;
    for (int i = threadIdx.x; i < 4096; i += 256) {
        float v = b2f(x[i]);
        if (!(fabsf(v) < 1e6f)) bad++;   // NaN compares false -> counted
    }
    atomicAdd(&cnt, bad);
    __syncthreads();
    if (threadIdx.x == 0) *flag = (cnt > 256) ? 1 : 0;
}

// ---------------------------------------------------------------------------
// convert kernel: f32 -> bf16 (flag==1) or bf16 copy (flag==0). n % 8 == 0.
// ---------------------------------------------------------------------------
__global__ __launch_bounds__(256) void conv_k(const void* __restrict__ src,
                                              uint16_t* __restrict__ dst,
                                              size_t n,
                                              const int* __restrict__ flagp) {
    const int f = *flagp;
    size_t i = ((size_t)blockIdx.x * blockDim.x + threadIdx.x) * 8;
    const size_t stride = (size_t)gridDim.x * blockDim.x * 8;
    if (f) {
        for (; i < n; i += stride) {
            const float* s = (const float*)src + i;
            u16x8 r;
#pragma unroll
            for (int j = 0; j < 8; ++j) r[j] = f2b(s[j]);
            *(u16x8*)(dst + i) = r;
        }
    } else {
        for (; i < n; i += stride)
            *(u16x8*)(dst + i) = *(const u16x8*)((const uint16_t*)src + i);
    }
}

// ---------------------------------------------------------------------------
// fused 4-region convert: one launch for x, wq, wk, wv (saves launch gaps).
// ---------------------------------------------------------------------------
__global__ __launch_bounds__(256) void conv4_k(const void* __restrict__ s0,
                                               const void* __restrict__ s1,
                                               const void* __restrict__ s2,
                                               const void* __restrict__ s3,
                                               uint16_t* __restrict__ d0,
                                               uint16_t* __restrict__ d1,
                                               uint16_t* __restrict__ d2,
                                               uint16_t* __restrict__ d3,
                                               size_t n0, size_t n1,
                                               size_t n2, size_t n3,
                                               const int* __restrict__ flagp) {
    const int f = *flagp;
    const size_t tot = (n0 + n1 + n2 + n3) >> 3;
    size_t c = (size_t)blockIdx.x * blockDim.x + threadIdx.x;
    const size_t stride = (size_t)gridDim.x * blockDim.x;
    for (; c < tot; c += stride) {
        size_t off = c << 3;
        const void* sp; uint16_t* dp;
        if (off < n0) { sp = s0; dp = d0; }
        else {
            off -= n0;
            if (off < n1) { sp = s1; dp = d1; }
            else {
                off -= n1;
                if (off < n2) { sp = s2; dp = d2; }
                else { off -= n2; sp = s3; dp = d3; }
            }
        }
        if (f) {
            const float* s = (const float*)sp + off;
            u16x8 r;
#pragma unroll
            for (int j = 0; j < 8; ++j) r[j] = f2b(s[j]);
            *(u16x8*)(dp + off) = r;
        } else {
            *(u16x8*)(dp + off) = *(const u16x8*)((const uint16_t*)sp + off);
        }
    }
}

// ---------------------------------------------------------------------------
// Legacy NT GEMM (fallback when workspace too small): dynamic dtype operands.
// out_trans: write C^T (bf16) at CT[col][row], ldc = row stride of CT.
// ---------------------------------------------------------------------------
__global__ __launch_bounds__(256) void gemm_nt(const void* __restrict__ A,
                                               const void* __restrict__ B,
                                               void* __restrict__ C,
                                               int K, int ldc,
                                               const int* __restrict__ flagp,
                                               int a_dyn, int b_dyn, int out_dyn,
                                               int out_trans) {
    __shared__ uint16_t As[128 * 64];
    __shared__ uint16_t Bs[128 * 64];
    const int f = *flagp;
    const bool af32 = a_dyn && f, bf32 = b_dyn && f, of32 = out_dyn && f;
    const int tid = threadIdx.x;
    const int wave = tid >> 6, lane = tid & 63;
    const int wh = wave >> 1, ww = wave & 1;
    const int quad = lane >> 4, l16 = lane & 15;
    const int m0 = blockIdx.x * 128;
    const int n0 = blockIdx.y * 128;

    floatx4 acc[4][4] = {};

    for (int k0 = 0; k0 < K; k0 += 64) {
        __syncthreads();
#pragma unroll
        for (int it = 0; it < 4; ++it) {
            int id = tid + it * 256;
            int row = id >> 3, slot = id & 7;
            int c8 = ((slot ^ (row & 7)) << 3);
            u16x8 va = ldchunk(A, af32, (size_t)(m0 + row) * K + k0 + c8);
            *(u16x8*)(As + row * 64 + slot * 8) = va;
            u16x8 vb = ldchunk(B, bf32, (size_t)(n0 + row) * K + k0 + c8);
            *(u16x8*)(Bs + row * 64 + slot * 8) = vb;
        }
        __syncthreads();
#pragma unroll
        for (int ks = 0; ks < 2; ++ks) {
            bf16x8 af[4], bf[4];
#pragma unroll
            for (int mi = 0; mi < 4; ++mi) {
                int r = wh * 64 + mi * 16 + l16;
                int slot = (ks * 4 + quad) ^ (r & 7);
                af[mi] = *(const bf16x8*)(As + r * 64 + slot * 8);
            }
#pragma unroll
            for (int ni = 0; ni < 4; ++ni) {
                int r = ww * 64 + ni * 16 + l16;
                int slot = (ks * 4 + quad) ^ (r & 7);
                bf[ni] = *(const bf16x8*)(Bs + r * 64 + slot * 8);
            }
#pragma unroll
            for (int mi = 0; mi < 4; ++mi)
#pragma unroll
                for (int ni = 0; ni < 4; ++ni)
                    acc[mi][ni] = __builtin_amdgcn_mfma_f32_16x16x32_bf16(
                        af[mi], bf[ni], acc[mi][ni], 0, 0, 0);
        }
    }
#pragma unroll
    for (int mi = 0; mi < 4; ++mi) {
#pragma unroll
        for (int ni = 0; ni < 4; ++ni) {
            int row = m0 + wh * 64 + mi * 16 + quad * 4;
            int col = n0 + ww * 64 + ni * 16 + l16;
            if (out_trans) {
                uint64_t pack = 0;
#pragma unroll
                for (int i = 0; i < 4; ++i)
                    pack |= (uint64_t)f2b(acc[mi][ni][i]) << (16 * i);
                *(uint64_t*)((uint16_t*)C + (size_t)col * ldc + row) = pack;
            } else if (of32) {
#pragma unroll
                for (int i = 0; i < 4; ++i)
                    ((float*)C)[(size_t)(row + i) * ldc + col] = acc[mi][ni][i];
            } else {
#pragma unroll
                for (int i = 0; i < 4; ++i)
                    ((uint16_t*)C)[(size_t)(row + i) * ldc + col] = f2b(acc[mi][ni][i]);
            }
        }
    }
}

// ---------------------------------------------------------------------------
// Fast NT GEMM: pure bf16 operands, global_load_lds(16B) staging.
// XCD-chunked bijective blockIdx swizzle when nwg%8==0.
// out_mode: 0 = bf16 row-major; 1 = f32-if-flag row-major.
// ---------------------------------------------------------------------------
__global__ __launch_bounds__(256) void gemm_bf(const uint16_t* __restrict__ A,
                                               const uint16_t* __restrict__ B,
                                               void* __restrict__ C,
                                               int K, int ldc,
                                               const int* __restrict__ flagp,
                                               int out_mode) {
    __shared__ uint16_t As[128 * 64];
    __shared__ uint16_t Bs[128 * 64];
    const bool of32 = (out_mode == 1) && (*flagp);
    const int tid = threadIdx.x;
    const int wave = tid >> 6, lane = tid & 63;
    const int wh = wave >> 1, ww = wave & 1;
    const int quad = lane >> 4, l16 = lane & 15;

    int nwg = gridDim.x * gridDim.y;
    int id = blockIdx.y * gridDim.x + blockIdx.x;
    if ((nwg & 7) == 0) {
        int cpx = nwg >> 3;
        id = (id & 7) * cpx + (id >> 3);
    }
    const int m0 = (id % gridDim.x) * 128;
    const int n0 = (id / gridDim.x) * 128;

    floatx4 acc[4][4] = {};

    for (int k0 = 0; k0 < K; k0 += 64) {
        __syncthreads();   // prior iteration's LDS reads done
#pragma unroll
        for (int it = 0; it < 4; ++it) {
            int idc = tid + it * 256;          // chunk id 0..1023
            int row = idc >> 3, slot = idc & 7;
            int c8 = ((slot ^ (row & 7)) << 3);
            __builtin_amdgcn_global_load_lds(
                AS1C(A + (size_t)(m0 + row) * K + k0 + c8),
                AS3(As + (size_t)(it * 256 + wave * 64) * 8), 16, 0, 0);
            __builtin_amdgcn_global_load_lds(
                AS1C(B + (size_t)(n0 + row) * K + k0 + c8),
                AS3(Bs + (size_t)(it * 256 + wave * 64) * 8), 16, 0, 0);
        }
        __syncthreads();   // vmcnt(0) drain + barrier: tiles visible
#pragma unroll
        for (int ks = 0; ks < 2; ++ks) {
            bf16x8 af[4], bf[4];
#pragma unroll
            for (int mi = 0; mi < 4; ++mi) {
                int r = wh * 64 + mi * 16 + l16;
                int slot = (ks * 4 + quad) ^ (r & 7);
                af[mi] = *(const bf16x8*)(As + r * 64 + slot * 8);
            }
#pragma unroll
            for (int ni = 0; ni < 4; ++ni) {
                int r = ww * 64 + ni * 16 + l16;
                int slot = (ks * 4 + quad) ^ (r & 7);
                bf[ni] = *(const bf16x8*)(Bs + r * 64 + slot * 8);
            }
#pragma unroll
            for (int mi = 0; mi < 4; ++mi)
#pragma unroll
                for (int ni = 0; ni < 4; ++ni)
                    acc[mi][ni] = __builtin_amdgcn_mfma_f32_16x16x32_bf16(
                        af[mi], bf[ni], acc[mi][ni], 0, 0, 0);
        }
    }
    // epilogue: C/D layout row = quad*4 + i, col = lane&15
#pragma unroll
    for (int mi = 0; mi < 4; ++mi) {
#pragma unroll
        for (int ni = 0; ni < 4; ++ni) {
            int row = m0 + wh * 64 + mi * 16 + quad * 4;
            int col = n0 + ww * 64 + ni * 16 + l16;
            if (of32) {
#pragma unroll
                for (int i = 0; i < 4; ++i)
                    ((float*)C)[(size_t)(row + i) * ldc + col] = acc[mi][ni][i];
            } else {
#pragma unroll
                for (int i = 0; i < 4; ++i)
                    ((uint16_t*)C)[(size_t)(row + i) * ldc + col] = f2b(acc[mi][ni][i]);
            }
        }
    }
}

// ---------------------------------------------------------------------------
// Fused QKV projection GEMM: A = xb [SEQ][DIM], W = [QKVDIM][DIM] (rows
// 0..4095 wq, 4096..5119 wk, 5120..6143 wv). Epilogue routes by n0:
// Q -> Qo row-major [SEQ][DIM]; K -> Ko row-major [SEQ][KVDIM];
// V -> VoT transposed [KVDIM][SEQ] (attn consumes V^T).
// grid 16x48 = 768 blocks (3/CU), XCD-chunked swizzle.
// ---------------------------------------------------------------------------
__global__ __launch_bounds__(256) void gemm_qkv(const uint16_t* __restrict__ A,
                                                const uint16_t* __restrict__ W,
                                                uint16_t* __restrict__ Qo,
                                                uint16_t* __restrict__ Ko,
                                                uint16_t* __restrict__ VoT) {
    __shared__ uint16_t As[128 * 64];
    __shared__ uint16_t Bs[128 * 64];
    const int tid = threadIdx.x;
    const int wave = tid >> 6, lane = tid & 63;
    const int wh = wave >> 1, ww = wave & 1;
    const int quad = lane >> 4, l16 = lane & 15;

    int nwg = gridDim.x * gridDim.y;           // 768
    int id = blockIdx.y * gridDim.x + blockIdx.x;
    int cpx = nwg >> 3;
    id = (id & 7) * cpx + (id >> 3);           // XCD-chunked, M fastest
    const int m0 = (id % gridDim.x) * 128;
    const int n0 = (id / gridDim.x) * 128;
    const int K = DIM;

    floatx4 acc[4][4] = {};

    for (int k0 = 0; k0 < K; k0 += 64) {
        __syncthreads();
#pragma unroll
        for (int it = 0; it < 4; ++it) {
            int idc = tid + it * 256;
            int row = idc >> 3, slot = idc & 7;
            int c8 = ((slot ^ (row & 7)) << 3);
            __builtin_amdgcn_global_load_lds(
                AS1C(A + (size_t)(m0 + row) * K + k0 + c8),
                AS3(As + (size_t)(it * 256 + wave * 64) * 8), 16, 0, 0);
            __builtin_amdgcn_global_load_lds(
                AS1C(W + (size_t)(n0 + row) * K + k0 + c8),
                AS3(Bs + (size_t)(it * 256 + wave * 64) * 8), 16, 0, 0);
        }
        __syncthreads();
#pragma unroll
        for (int ks = 0; ks < 2; ++ks) {
            bf16x8 af[4], bf[4];
#pragma unroll
            for (int mi = 0; mi < 4; ++mi) {
                int r = wh * 64 + mi * 16 + l16;
                int slot = (ks * 4 + quad) ^ (r & 7);
                af[mi] = *(const bf16x8*)(As + r * 64 + slot * 8);
            }
#pragma unroll
            for (int ni = 0; ni < 4; ++ni) {
                int r = ww * 64 + ni * 16 + l16;
                int slot = (ks * 4 + quad) ^ (r & 7);
                bf[ni] = *(const bf16x8*)(Bs + r * 64 + slot * 8);
            }
#pragma unroll
            for (int mi = 0; mi < 4; ++mi)
#pragma unroll
                for (int ni = 0; ni < 4; ++ni)
                    acc[mi][ni] = __builtin_amdgcn_mfma_f32_16x16x32_bf16(
                        af[mi], bf[ni], acc[mi][ni], 0, 0, 0);
        }
    }
    // epilogue: slice-routed (n0 uniform per block; slices 128-aligned)
#pragma unroll
    for (int mi = 0; mi < 4; ++mi) {
#pragma unroll
        for (int ni = 0; ni < 4; ++ni) {
            int row = m0 + wh * 64 + mi * 16 + quad * 4;
            int col = n0 + ww * 64 + ni * 16 + l16;
            if (n0 < DIM) {
#pragma unroll
                for (int i = 0; i < 4; ++i)
                    Qo[(size_t)(row + i) * DIM + col] = f2b(acc[mi][ni][i]);
            } else if (n0 < DIM + KVDIM) {
                int c = col - DIM;
#pragma unroll
                for (int i = 0; i < 4; ++i)
                    Ko[(size_t)(row + i) * KVDIM + c] = f2b(acc[mi][ni][i]);
            } else {
                int c = col - DIM - KVDIM;
                uint64_t pack = 0;
#pragma unroll
                for (int i = 0; i < 4; ++i)
                    pack |= (uint64_t)f2b(acc[mi][ni][i]) << (16 * i);
                *(uint64_t*)(VoT + (size_t)c * SEQ + row) = pack;
            }
        }
    }
}

// ---------------------------------------------------------------------------
// Fused RoPE: one launch for Q [SEQ][DIM] and K [SEQ][KVDIM]. Head-slot
// hh in [0,40): hh<32 -> Q head hh, else K head hh-32. hh is wave-uniform.
// ---------------------------------------------------------------------------
__global__ void rope2_k(uint16_t* __restrict__ Qb, uint16_t* __restrict__ Kb) {
    int id = blockIdx.x * blockDim.x + threadIdx.x;
    int i = id & 63;
    int rest = id >> 6;
    int hh = rest % (NH + NKV);
    int t = rest / (NH + NKV);
    uint16_t* p = (hh < NH)
        ? (Qb + (size_t)t * DIM + hh * HD + 2 * i)
        : (Kb + (size_t)t * KVDIM + (hh - NH) * HD + 2 * i);
    float e = b2f(p[0]), o = b2f(p[1]);
    float freq = exp2f(-(float)(2 * i) * (18.93156857f / 128.0f));
    float ang = (float)t * freq;
    float s, c;
    sincosf(ang, &s, &c);
    p[0] = f2b(e * c - o * s);
    p[1] = f2b(e * s + o * c);
}

// ---------------------------------------------------------------------------
// Flash attention (causal, GQA rep=4). 512 threads = 8 waves; wave w owns
// q-rows [w*16, w*16+16). SWAPPED QK^T (mfma(K,Q) -> S^T rows=keys cols=q):
// each lane holds 16 scores for ONE q-row (q = l16) -> row max/sum are
// 15 local ops + 2 shfl_xor rounds (vs 4 chains x 8 rounds).
// T13 defer-rescale (THR=8): acc_o rescale + alpha broadcast skipped unless
// __any(pmax > m_run + 8); math exact (O invariant to m shift, P <= e^8).
// Pair-blocks: block does q-tiles (pairid, 15-pairid) = uniform 36 units,
// grid 256 = 1/CU. Q direct global->reg (no Qs; LDS 80 KB). K/V double-
// buffered via global_load_lds prefetch, drained at end-of-tile barrier.
// P buffer rows wave-exclusive (no mid-tile cross-wave barrier).
// ---------------------------------------------------------------------------
__global__ __launch_bounds__(512, 1) void attn_k(const uint16_t* __restrict__ Q,
                                                 const uint16_t* __restrict__ Kg,
                                                 const uint16_t* __restrict__ VgT,
                                                 uint16_t* __restrict__ O) {
    __shared__ uint16_t Ks[2][64 * 128];   // 32 KB
    __shared__ uint16_t Vt[2][128 * 64];   // 32 KB
    __shared__ uint16_t Pb[128 * 64];      // 16 KB  -> 80 KB total

    const int tid = threadIdx.x;
    const int wave = tid >> 6, lane = tid & 63;
    const int quad = lane >> 4, l16 = lane & 15;

    const int head = blockIdx.x & 31;
    const int pairid = blockIdx.x >> 5;      // 0..7
    const int kvh = head >> 2;
    const uint16_t* Vh = VgT + (size_t)kvh * HD * SEQ;

    const float scale = 0.08838834764831845f;  // 1/sqrt(128)
    const float LOG2E = 1.44269504f;

    auto stage_kv = [&](int buf, int k0s) {
#pragma unroll
        for (int it = 0; it < 2; ++it) {
            int id = tid + it * 512;
            int row = id >> 4, slot = id & 15;
            int c8 = ((slot ^ (row & 7)) << 3);
            __builtin_amdgcn_global_load_lds(
                AS1C(Kg + (size_t)(k0s + row) * KVDIM + kvh * HD + c8),
                AS3(Ks[buf] + (size_t)(it * 512 + wave * 64) * 8), 16, 0, 0);
        }
#pragma unroll
        for (int it = 0; it < 2; ++it) {
            int id = tid + it * 512;
            int d = id >> 3, slot = id & 7;
            int c8 = ((slot ^ (d & 7)) << 3);
            __builtin_amdgcn_global_load_lds(
                AS1C(Vh + (size_t)d * SEQ + k0s + c8),
                AS3(Vt[buf] + (size_t)(it * 512 + wave * 64) * 8), 16, 0, 0);
        }
    };

    int g = 0;   // global tile counter (LDS buffer parity)
    stage_kv(0, 0);
    __syncthreads();   // tile 0 visible

    for (int half = 0; half < 2; ++half) {
        const int qt = half ? (15 - pairid) : pairid;
        const int q0 = qt * 128;
        const int nkt = 2 * qt + 2;
        const int qrow_l = q0 + wave * 16 + l16;   // this lane's q-row (cols of S^T)

        // Q fragments: direct global -> registers (B-operand layout)
        bf16x8 qf[4];
        {
            const uint16_t* qrow = Q + (size_t)qrow_l * DIM + head * HD;
#pragma unroll
            for (int ks = 0; ks < 4; ++ks)
                qf[ks] = *(const bf16x8*)(qrow + (ks * 4 + quad) * 8);
        }

        floatx4 acc_o[8] = {};
        float m_run = -__builtin_inff(), l_run = 0.f;

        for (int t = 0; t < nkt; ++t, ++g) {
            const int k0 = t * 64;
            const bool diag = (t >= 2 * qt);
            const int cur = g & 1;

            // prefetch next tile (possibly the other half's tile 0)
            if (!(half == 1 && t == nkt - 1)) {
                int k0n = (t + 1 < nkt) ? (t + 1) * 64 : 0;
                stage_kv((g + 1) & 1, k0n);
            }
            __builtin_amdgcn_sched_barrier(0);   // pin prefetch issue early

            // S^T = K Q^T : rows = keys (ni*16 + quad*4 + i), cols = q (l16)
            floatx4 acc_s[4] = {};
            __builtin_amdgcn_s_setprio(1);
#pragma unroll
            for (int ks = 0; ks < 4; ++ks) {
                bf16x8 kf[4];
#pragma unroll
                for (int ni = 0; ni < 4; ++ni) {
                    int r = ni * 16 + l16;
                    int slot = (ks * 4 + quad) ^ (r & 7);
                    kf[ni] = *(const bf16x8*)(Ks[cur] + r * 128 + slot * 8);
                }
#pragma unroll
                for (int ni = 0; ni < 4; ++ni)
                    acc_s[ni] = __builtin_amdgcn_mfma_f32_16x16x32_bf16(
                        kf[ni], qf[ks], acc_s[ni], 0, 0, 0);
            }
            __builtin_amdgcn_s_setprio(0);

            // scale + causal mask (lane's q-row fixed = qrow_l)
#pragma unroll
            for (int ni = 0; ni < 4; ++ni)
#pragma unroll
                for (int i = 0; i < 4; ++i) {
                    float s = acc_s[ni][i] * scale;
                    if (diag) {
                        int kl = k0 + ni * 16 + quad * 4 + i;
                        if (kl > qrow_l) s = -__builtin_inff();
                    }
                    acc_s[ni][i] = s;
                }

            // row max: 15 local fmax + 2 cross-quad rounds
            float pmax;
            {
                float v0 = fmaxf(fmaxf(acc_s[0][0], acc_s[0][1]), fmaxf(acc_s[0][2], acc_s[0][3]));
                float v1 = fmaxf(fmaxf(acc_s[1][0], acc_s[1][1]), fmaxf(acc_s[1][2], acc_s[1][3]));
                float v2 = fmaxf(fmaxf(acc_s[2][0], acc_s[2][1]), fmaxf(acc_s[2][2], acc_s[2][3]));
                float v3 = fmaxf(fmaxf(acc_s[3][0], acc_s[3][1]), fmaxf(acc_s[3][2], acc_s[3][3]));
                pmax = fmaxf(fmaxf(v0, v1), fmaxf(v2, v3));
                pmax = fmaxf(pmax, __shfl_xor(pmax, 16));
                pmax = fmaxf(pmax, __shfl_xor(pmax, 32));
            }

            // T13 defer-rescale: only rescale when max grew past threshold
            if (__any(pmax > m_run + 8.0f)) {
                float mn = fmaxf(m_run, pmax);
                float alpha = exp2f((m_run - mn) * LOG2E);
                m_run = mn;
                l_run *= alpha;
                float aq[4];
#pragma unroll
                for (int i = 0; i < 4; ++i)
                    aq[i] = __shfl(alpha, quad * 4 + i);   // alpha for acc row quad*4+i
#pragma unroll
                for (int ni = 0; ni < 8; ++ni)
#pragma unroll
                    for (int i = 0; i < 4; ++i)
                        acc_o[ni][i] *= aq[i];
            }

            // P = exp(s - m) -> bf16 into wave-owned Pb rows; row sum
            {
                const int ql = wave * 16 + l16;
                const int swz = (ql & 7) ^ ((ql >> 3) & 7);
                uint16_t* prow = Pb + ql * 64;
                float sum = 0.f;
#pragma unroll
                for (int ni = 0; ni < 4; ++ni)
#pragma unroll
                    for (int i = 0; i < 4; ++i) {
                        float p = exp2f((acc_s[ni][i] - m_run) * LOG2E);
                        sum += p;
                        int key = ni * 16 + quad * 4 + i;
                        int slot = ((key >> 3) ^ swz) & 7;
                        prow[slot * 8 + (key & 7)] = f2b(p);
                    }
                sum += __shfl_xor(sum, 16);
                sum += __shfl_xor(sum, 32);
                l_run += sum;
            }

            // O += P V  (P rows wave-exclusive: same-wave DS order suffices)
            __builtin_amdgcn_s_setprio(1);
#pragma unroll
            for (int ks2 = 0; ks2 < 2; ++ks2) {
                bf16x8 pf, vf[8];
                {
                    int r = wave * 16 + l16;
                    int slot = ((ks2 * 4 + quad) ^ (r & 7) ^ ((r >> 3) & 7)) & 7;
                    pf = *(const bf16x8*)(Pb + r * 64 + slot * 8);
                }
#pragma unroll
                for (int ni = 0; ni < 8; ++ni) {
                    int d = ni * 16 + l16;
                    int slot = ((ks2 * 4 + quad) ^ (d & 7)) & 7;
                    vf[ni] = *(const bf16x8*)(Vt[cur] + d * 64 + slot * 8);
                }
#pragma unroll
                for (int ni = 0; ni < 8; ++ni)
                    acc_o[ni] = __builtin_amdgcn_mfma_f32_16x16x32_bf16(
                        pf, vf[ni], acc_o[ni], 0, 0, 0);
            }
            __builtin_amdgcn_s_setprio(0);

            __syncthreads();   // drains prefetch (vmcnt) + all LDS; next tile ready
        }

        // ---- epilogue for this q-tile ----
        {
            float inv = 1.0f / l_run;          // for q-row l16
            float invq[4];
#pragma unroll
            for (int i = 0; i < 4; ++i)
                invq[i] = __shfl(inv, quad * 4 + i);
#pragma unroll
            for (int i = 0; i < 4; ++i) {
                int row = q0 + wave * 16 + quad * 4 + i;
#pragma unroll
                for (int ni = 0; ni < 8; ++ni) {
                    int col = head * HD + ni * 16 + l16;
                    O[(size_t)row * DIM + col] = f2b(acc_o[ni][i] * invq[i]);
                }
            }
        }
    }
}

extern "C" void kernel_launch(void* const* d_in, const int* in_sizes, int n_in,
                              void* d_out, int out_size, void* d_ws, size_t ws_size,
                              hipStream_t stream) {
    const void* x  = d_in[0];
    const void* wq = d_in[1];
    const void* wk = d_in[2];
    const void* wv = d_in[3];
    const void* wo = d_in[4];

    // fast-path ws layout (aliased, stream-ordered):
    //   [flag 256B][Kb 4M][VbT 4M][xb 16M][BIG 50.3M]
    //   BIG = Wqkv[6144][4096] during QKV gemm;
    //   then Ab = BIG[0:16.8M] (attn out), Wo = BIG+16.8M (wo bf16, 33.6M).
    int* flag = (int*)d_ws;
    uint16_t* Kb  = (uint16_t*)((char*)d_ws + 256);
    uint16_t* VbT = Kb + (size_t)SEQ * KVDIM;       // V^T: [KVDIM][SEQ]
    uint16_t* xb  = VbT + (size_t)SEQ * KVDIM;
    uint16_t* BIG = xb + (size_t)SEQ * DIM;
    uint16_t* Wqkv = BIG;
    uint16_t* Ab   = BIG;
    uint16_t* Wo   = BIG + (size_t)SEQ * DIM;
    // Q lives in d_out (dead before the final GEMM overwrites d_out)
    uint16_t* Qb = (uint16_t*)d_out;

    const size_t need = 256 + ((size_t)2 * SEQ * KVDIM     // Kb + VbT
                             + (size_t)SEQ * DIM           // xb
                             + (size_t)QKVDIM * DIM) * 2;  // BIG

    dim3 blk(256);
    detect_k<<<1, blk, 0, stream>>>((const uint16_t*)x, flag);

    if (ws_size >= need) {
        // fast path: fused pre-convert, fused QKV gemm, global_load_lds
        conv4_k<<<4096, blk, 0, stream>>>(
            x, wq, wk, wv,
            xb, Wqkv, Wqkv + (size_t)DIM * DIM, Wqkv + (size_t)(DIM + KVDIM) * DIM,
            (size_t)SEQ * DIM, (size_t)DIM * DIM,
            (size_t)KVDIM * DIM, (size_t)KVDIM * DIM, flag);
        gemm_qkv<<<dim3(SEQ / 128, QKVDIM / 128), blk, 0, stream>>>(
            xb, Wqkv, Qb, Kb, VbT);
        // Wqkv dead; Wo region (BIG+16.8M) safe to fill now
        conv_k<<<2048, blk, 0, stream>>>(wo, Wo, (size_t)DIM * DIM, flag);
        rope2_k<<<(SEQ * (NH + NKV) * 64) / 256, 256, 0, stream>>>(Qb, Kb);
        attn_k<<<NH * 8, dim3(512), 0, stream>>>(Qb, Kb, VbT, Ab);   // Ab = BIG[0:16.8M]
        gemm_bf<<<dim3(SEQ / 128, DIM / 128), blk, 0, stream>>>(Ab, Wo, d_out, DIM, DIM, flag, 1);
    } else {
        // legacy path: dynamic-dtype GEMMs, no extra workspace
        uint16_t* AbL = xb;   // legacy Ab right after VbT (within 'fixed' size)
        gemm_nt<<<dim3(SEQ / 128, DIM / 128), blk, 0, stream>>>(x, wq, Qb, DIM, DIM, flag, 1, 1, 0, 0);
        gemm_nt<<<dim3(SEQ / 128, KVDIM / 128), blk, 0, stream>>>(x, wk, Kb, DIM, KVDIM, flag, 1, 1, 0, 0);
        gemm_nt<<<dim3(SEQ / 128, KVDIM / 128), blk, 0, stream>>>(x, wv, VbT, DIM, SEQ, flag, 1, 1, 0, 1);
        rope2_k<<<(SEQ * (NH + NKV) * 64) / 256, 256, 0, stream>>>(Qb, Kb);
        attn_k<<<NH * 8, dim3(512), 0, stream>>>(Qb, Kb, VbT, AbL);
        gemm_nt<<<dim3(SEQ / 128, DIM / 128), blk, 0, stream>>>(AbL, wo, d_out, DIM, DIM, flag, 0, 1, 1, 0);
    }
}